// Round 4
// baseline (64.410 us; speedup 1.0000x reference)
//
#include <hip/hip_runtime.h>
#include <hip/hip_cooperative_groups.h>
#include <math.h>

namespace cg = cooperative_groups;

#define T_STEPS 1000000
#define BLOCK 256
#define ITEMS 8
#define CHUNK (BLOCK * ITEMS)               // 2048
#define NB ((T_STEPS + CHUNK - 1) / CHUNK)  // 489
#define NF4 (T_STEPS / 2)                   // 500000 float4 of controls
#define PER 2                               // aggregates per thread in compose (489 <= 512)

// ---- wave/block scan helpers (fp64, shfl-based, 1 barrier each) ---------

__device__ __forceinline__ double waveScanIncl(double v) {
#pragma unroll
    for (int off = 1; off < 64; off <<= 1) {
        double x = __shfl_up(v, off, 64);
        if ((threadIdx.x & 63) >= off) v += x;
    }
    return v;
}

// exclusive prefix over the block's per-thread values; *tot = block total
__device__ __forceinline__ double blockScanEx(double v, double* sw, double* tot) {
    const int lane = threadIdx.x & 63, w = threadIdx.x >> 6;
    double inc = waveScanIncl(v);
    if (lane == 63) sw[w] = inc;
    __syncthreads();
    double w0 = sw[0], w1 = sw[1], w2 = sw[2], w3 = sw[3];
    __syncthreads();
    *tot = w0 + w1 + w2 + w3;
    double woff = (w > 0 ? w0 : 0.0) + (w > 1 ? w1 : 0.0) + (w > 2 ? w2 : 0.0);
    return woff + inc - v;
}

__device__ __forceinline__ double blockSum(double v, double* sw) {
#pragma unroll
    for (int off = 32; off > 0; off >>= 1) v += __shfl_xor(v, off, 64);
    const int lane = threadIdx.x & 63, w = threadIdx.x >> 6;
    if (lane == 0) sw[w] = v;
    __syncthreads();
    double r = sw[0] + sw[1] + sw[2] + sw[3];
    __syncthreads();
    return r;
}

// fp64 range reduction -> HW v_sin_f32/v_cos_f32 (abs err ~1e-6)
__device__ __forceinline__ void ftrig(double th, double& cs, double& sn) {
    const double INV2PI = 0.15915494309189535;
    double rev = th * INV2PI;
    double fr = rev - rint(rev);                 // [-0.5, 0.5]
    float x = (float)fr * 6.283185307179586f;
    sn = (double)__sinf(x);
    cs = (double)__cosf(x);
}

// ---- fused: aggregates -> grid sync -> compose -> output ----------------

__global__ void __launch_bounds__(BLOCK, 2) k_fused(
    const float4* __restrict__ ctrl4, const float* __restrict__ sp,
    float4* __restrict__ out4, float* __restrict__ traj,
    double* __restrict__ aggTh, double* __restrict__ aggA,
    double* __restrict__ aggB) {
    __shared__ double sw[4];
    const int b = blockIdx.x, t = threadIdx.x;
    const int f0 = b * (CHUNK / 2) + t * (ITEMS / 2);

    // -- phase A: load, passthrough, local rigid-motion aggregate --
    float4 c4[ITEMS / 2];
#pragma unroll
    for (int j = 0; j < ITEMS / 2; ++j) {
        int f = f0 + j;
        c4[j] = (f < NF4) ? ctrl4[f] : make_float4(0.f, 0.f, 0.f, 0.f);
    }
#pragma unroll
    for (int j = 0; j < ITEMS / 2; ++j) {
        int f = f0 + j;
        if (f < NF4) out4[f] = c4[j];  // controls passthrough output
    }

    double dth[ITEMS];
    double lth = 0.0;
#pragma unroll
    for (int j = 0; j < ITEMS / 2; ++j) {
        dth[2 * j]     = 10.0 * (double)c4[j].y;
        dth[2 * j + 1] = 10.0 * (double)c4[j].w;
        lth += dth[2 * j] + dth[2 * j + 1];
    }
    double thTot;
    double thb = blockScanEx(lth, sw, &thTot);  // local angle before 1st owned elem

    double av[ITEMS], bv[ITEMS];
    double la = 0.0, lb = 0.0;
    {
        double run = thb;
#pragma unroll
        for (int j = 0; j < ITEMS / 2; ++j) {
            double s0 = fabs((double)c4[j].x);
            double s1 = fabs((double)c4[j].z);
            double cs, sn;
            ftrig(run, cs, sn);
            av[2 * j] = s0 * cs; bv[2 * j] = s0 * sn;
            run += dth[2 * j];
            ftrig(run, cs, sn);
            av[2 * j + 1] = s1 * cs; bv[2 * j + 1] = s1 * sn;
            run += dth[2 * j + 1];
            la += av[2 * j] + av[2 * j + 1];
            lb += bv[2 * j] + bv[2 * j + 1];
        }
    }
    double A = blockSum(la, sw);
    double B = blockSum(lb, sw);
    if (t == 0) {
        aggTh[b] = thTot;
        aggA[b]  = A;
        aggB[b]  = B;
    }

    // -- grid-wide barrier: all aggregates published & visible --
    cg::this_grid().sync();

    // -- phase B: entry state (Xin, Yin, psi) from predecessor aggregates --
    const double x0 = (double)sp[0], y0 = (double)sp[1], th0 = (double)sp[2];

    double pTh[PER], pA[PER], pB[PER];
    double lsum = 0.0;
#pragma unroll
    for (int k = 0; k < PER; ++k) {
        int p = t * PER + k;
        if (p < NB) {
            pTh[k] = aggTh[p];
            pA[k]  = aggA[p];
            pB[k]  = aggB[p];
        } else {
            pTh[k] = pA[k] = pB[k] = 0.0;
        }
        lsum += pTh[k];
    }
    double dummyTot;
    double excl = blockScanEx(lsum, sw, &dummyTot);  // theta prefix before my slots

    double cx = 0.0, cy = 0.0, mth = 0.0;
    {
        double run2 = th0 + excl;  // entry angle of aggregate p
#pragma unroll
        for (int k = 0; k < PER; ++k) {
            int p = t * PER + k;
            if (p < b) {
                double cs, sn;
                ftrig(run2, cs, sn);
                cx += cs * pA[k] - sn * pB[k];
                cy += sn * pA[k] + cs * pB[k];
                mth += pTh[k];
            }
            run2 += pTh[k];
        }
    }
    const double psi = th0 + blockSum(mth, sw);  // my block's entry angle
    const double Xin = x0 + blockSum(cx, sw);
    const double Yin = y0 + blockSum(cy, sw);
    double cps, sps;
    ftrig(psi, cps, sps);

    // -- phase C: finish with registers retained across the sync --
    double aTot, bTot;
    double Ar = blockScanEx(la, sw, &aTot);
    double Br = blockScanEx(lb, sw, &bTot);

    {
        const long e0 = (long)b * CHUNK + (long)t * ITEMS;
        double run = thb;
#pragma unroll
        for (int k = 0; k < ITEMS; ++k) {
            Ar += av[k];
            Br += bv[k];
            run += dth[k];
            long i = e0 + k;
            if (i < T_STEPS) {
                float* row = traj + 3 * (i + 1);
                row[0] = (float)(Xin + cps * Ar - sps * Br);
                row[1] = (float)(Yin + sps * Ar + cps * Br);
                row[2] = (float)(psi + run);
            }
        }
    }
    if (b == 0 && t == 0) {
        traj[0] = sp[0];
        traj[1] = sp[1];
        traj[2] = sp[2];
    }
}

// ---- launch --------------------------------------------------------------

extern "C" void kernel_launch(void* const* d_in, const int* in_sizes, int n_in,
                              void* d_out, int out_size, void* d_ws, size_t ws_size,
                              hipStream_t stream) {
    const float*  start_pose = (const float*)d_in[0];
    const float4* ctrl4      = (const float4*)d_in[1];

    float*  out  = (float*)d_out;
    float4* out4 = (float4*)out;                 // controls passthrough
    float*  traj = out + 2 * (long)T_STEPS;      // (T+1, 3)

    double* aggTh = (double*)d_ws;
    double* aggA  = aggTh + NB;
    double* aggB  = aggA + NB;

    void* kargs[] = {
        (void*)&ctrl4, (void*)&start_pose, (void*)&out4, (void*)&traj,
        (void*)&aggTh, (void*)&aggA, (void*)&aggB
    };
    hipLaunchCooperativeKernel((const void*)k_fused, dim3(NB), dim3(BLOCK),
                               kargs, 0, stream);
}